// Round 10
// baseline (335.942 us; speedup 1.0000x reference)
//
#include <hip/hip_runtime.h>
#include <hip/hip_cooperative_groups.h>
#include <math.h>

namespace cg = cooperative_groups;

#define N_NODES 100000
#define N_EDGES 6400000
#define K_BINS  4
#define BIN_SZ  25000          // N_NODES / 4 exactly; 100,000 B LDS -> 1 block/CU
#define BLOCK   1024
#define NXCD    8
#define LOG2_10 3.321928094887362f

// R10: fuse edge + node kernels into ONE cooperative launch.
// Evidence: total - edge ~= 101-107us in ALL rounds, invariant to node-side
// traffic (R4's node input 10x smaller: same residue) -> the residue is
// inter-dispatch overhead, not kernel work. Grid = 256 blocks x 100KB LDS =
// exactly 1 block/CU (cooperative co-residency trivially satisfied).
// Edge phase is byte-identical to the verified R9 kernel (edge 62us,
// model-validated 5 rounds straight). threadfence (device scope, cross-XCD
// part visibility) + grid.sync() replaces the kernel boundary.
__device__ __forceinline__ void proc4(const float* __restrict__ rates,
                                      float* __restrict__ bin, int base_node,
                                      int4 dd, int4 ss, float4 ww) {
    unsigned ex = (unsigned)(dd.x - base_node);
    unsigned ey = (unsigned)(dd.y - base_node);
    unsigned ez = (unsigned)(dd.z - base_node);
    unsigned ew = (unsigned)(dd.w - base_node);
    if (ex < BIN_SZ) atomicAdd(&bin[ex], rates[ss.x] * ww.x);
    if (ey < BIN_SZ) atomicAdd(&bin[ey], rates[ss.y] * ww.y);
    if (ez < BIN_SZ) atomicAdd(&bin[ez], rates[ss.z] * ww.z);
    if (ew < BIN_SZ) atomicAdd(&bin[ew], rates[ss.w] * ww.w);
}

__global__ __launch_bounds__(BLOCK) void fused_kernel(
        const float* __restrict__ rates,
        const float* __restrict__ weights,
        const float* __restrict__ gain,
        const float* __restrict__ time_constant,
        const float* __restrict__ baseline,
        const float* __restrict__ ext_input,
        const int*   __restrict__ src,
        const int*   __restrict__ dst,
        const int*   __restrict__ is_input,
        float* __restrict__ part,      // [n_chunks][N_NODES]
        float* __restrict__ out,
        int n_chunks, int edges_per_chunk) {
    __shared__ float bin[BIN_SZ];

    // ---------------- Phase 1: edge binning (verbatim R9) ----------------
    // Bijective XCD swizzle (m204): contiguous vbids per XCD => the 4 sibling
    // bin-blocks of a chunk share an XCD's L2 (R3-verified: FETCH 189->43 MB).
    const int nb  = gridDim.x;
    const int hb  = blockIdx.x;
    const int q   = nb / NXCD, r = nb % NXCD;
    const int xcd = hb % NXCD, pos = hb / NXCD;
    const int vbid = (xcd < r ? xcd * (q + 1) : r * (q + 1) + (xcd - r) * q) + pos;

    const int b = vbid % K_BINS;
    const int c = vbid / K_BINS;
    const int base_node = b * BIN_SZ;

    {
        float4* bz = (float4*)bin;
        const float4 z = make_float4(0.f, 0.f, 0.f, 0.f);
        for (int i = threadIdx.x; i < (BIN_SZ >> 2); i += BLOCK) bz[i] = z;
    }
    __syncthreads();

    const long e0 = (long)c * edges_per_chunk;
    const int nq = edges_per_chunk >> 4;              // groups of 16 edges
    const int4*   s4 = (const int4*)(src + e0);
    const int4*   d4 = (const int4*)(dst + e0);
    const float4* w4 = (const float4*)(weights + e0);

    for (int i = threadIdx.x; i < nq; i += BLOCK) {
        const int4*   dp = d4 + 4 * i;
        const int4*   sp = s4 + 4 * i;
        const float4* wp = w4 + 4 * i;
        int4   d0 = dp[0], d1 = dp[1], d2 = dp[2], d3 = dp[3];
        int4   sA = sp[0], sB = sp[1], sC = sp[2], sD = sp[3];
        float4 wA = wp[0], wB = wp[1], wC = wp[2], wD = wp[3];
        proc4(rates, bin, base_node, d0, sA, wA);
        proc4(rates, bin, base_node, d1, sB, wB);
        proc4(rates, bin, base_node, d2, sC, wC);
        proc4(rates, bin, base_node, d3, sD, wD);
    }
    __syncthreads();

    // Flush (K=4: 4*25000 == N_NODES, clamp kept for safety).
    const int flush_n = min(BIN_SZ, N_NODES - base_node);
    float4* outp = (float4*)(part + (size_t)c * N_NODES + base_node);
    const float4* binv = (const float4*)bin;
    for (int i = threadIdx.x; i < (flush_n >> 2); i += BLOCK) {
        outp[i] = binv[i];
    }

    // ------------- grid-wide barrier replaces kernel boundary -------------
    __threadfence();               // device scope: cross-XCD part visibility
    cg::this_grid().sync();

    // ---------------- Phase 2: node epilogue (verbatim R9 math) ----------
    const int total_t = gridDim.x * BLOCK;
    for (int t = blockIdx.x * BLOCK + threadIdx.x; t < (N_NODES >> 2); t += total_t) {
        float4 a0 = make_float4(0.f, 0.f, 0.f, 0.f);
        float4 a1 = make_float4(0.f, 0.f, 0.f, 0.f);
        float4 a2 = make_float4(0.f, 0.f, 0.f, 0.f);
        float4 a3 = make_float4(0.f, 0.f, 0.f, 0.f);
        int k = 0;
        for (; k + 3 < n_chunks; k += 4) {
            float4 p0 = ((const float4*)(part + (size_t)(k + 0) * N_NODES))[t];
            float4 p1 = ((const float4*)(part + (size_t)(k + 1) * N_NODES))[t];
            float4 p2 = ((const float4*)(part + (size_t)(k + 2) * N_NODES))[t];
            float4 p3 = ((const float4*)(part + (size_t)(k + 3) * N_NODES))[t];
            a0.x += p0.x; a0.y += p0.y; a0.z += p0.z; a0.w += p0.w;
            a1.x += p1.x; a1.y += p1.y; a1.z += p1.z; a1.w += p1.w;
            a2.x += p2.x; a2.y += p2.y; a2.z += p2.z; a2.w += p2.w;
            a3.x += p3.x; a3.y += p3.y; a3.z += p3.z; a3.w += p3.w;
        }
        for (; k < n_chunks; ++k) {
            float4 p = ((const float4*)(part + (size_t)k * N_NODES))[t];
            a0.x += p.x; a0.y += p.y; a0.z += p.z; a0.w += p.w;
        }
        float sx = (a0.x + a1.x) + (a2.x + a3.x);
        float sy = (a0.y + a1.y) + (a2.y + a3.y);
        float sz = (a0.z + a1.z) + (a2.z + a3.z);
        float sw = (a0.w + a1.w) + (a2.w + a3.w);

        float4 rr  = ((const float4*)rates)[t];
        float4 g   = ((const float4*)gain)[t];
        float4 tc  = ((const float4*)time_constant)[t];
        float4 bl  = ((const float4*)baseline)[t];
        float4 ext = ((const float4*)ext_input)[t];
        int4   ii  = ((const int4*)is_input)[t];

        float4 o;
        o.x = (-rr.x + exp2f(g.x * LOG2_10) * tanhf((ii.x ? ext.x : sx) + bl.x)) / tc.x;
        o.y = (-rr.y + exp2f(g.y * LOG2_10) * tanhf((ii.y ? ext.y : sy) + bl.y)) / tc.y;
        o.z = (-rr.z + exp2f(g.z * LOG2_10) * tanhf((ii.z ? ext.z : sz) + bl.z)) / tc.z;
        o.w = (-rr.w + exp2f(g.w * LOG2_10) * tanhf((ii.w ? ext.w : sw) + bl.w)) / tc.w;
        ((float4*)out)[t] = o;
    }
}

extern "C" void kernel_launch(void* const* d_in, const int* in_sizes, int n_in,
                              void* d_out, int out_size, void* d_ws, size_t ws_size,
                              hipStream_t stream) {
    const float* rates         = (const float*)d_in[0];
    const float* weights       = (const float*)d_in[1];
    const float* gain          = (const float*)d_in[2];
    const float* time_constant = (const float*)d_in[3];
    const float* baseline      = (const float*)d_in[4];
    const float* ext_input     = (const float*)d_in[5];
    const int*   src           = (const int*)d_in[6];
    const int*   dst           = (const int*)d_in[7];
    const int*   is_input      = (const int*)d_in[8];
    float* out  = (float*)d_out;
    float* part = (float*)d_ws;

    // 64 chunks -> grid 4*64 = 256 blocks = exactly 1 block/CU at 100 KB LDS
    // (cooperative co-residency guaranteed). 256 % 8 == 0 keeps the XCD
    // swizzle bijective and chunk-aligned (32 blocks = 8 whole chunks/XCD).
    // All candidates give edges_per_chunk % 16 == 0 and grid <= 256.
    static const int cand[] = {64, 32, 16, 8, 4, 2, 1};
    int n_chunks = 1;
    for (int i = 0; i < (int)(sizeof(cand)/sizeof(cand[0])); ++i) {
        if ((size_t)cand[i] * N_NODES * sizeof(float) <= ws_size) { n_chunks = cand[i]; break; }
    }
    int edges_per_chunk = N_EDGES / n_chunks;
    int grid_e = K_BINS * n_chunks;

    void* args[] = {
        (void*)&rates, (void*)&weights, (void*)&gain, (void*)&time_constant,
        (void*)&baseline, (void*)&ext_input, (void*)&src, (void*)&dst,
        (void*)&is_input, (void*)&part, (void*)&out,
        (void*)&n_chunks, (void*)&edges_per_chunk,
    };
    hipLaunchCooperativeKernel((const void*)fused_kernel, dim3(grid_e),
                               dim3(BLOCK), args, 0, stream);
}

// Round 11
// 170.640 us; speedup vs baseline: 1.9687x; 1.9687x over previous
//
#include <hip/hip_runtime.h>
#include <math.h>

#define N_NODES 100000
#define N_EDGES 6400000
#define K_BINS  4
#define BIN_SZ  25000          // N_NODES / 4 exactly; 100,000 B LDS -> 1 block/CU
#define BLOCK   1024
#define NXCD    8
#define LOG2_10 3.321928094887362f

// R11 = revert to R9 (verified best: edge 62us, total 166.9us).
// Session cost model (fitted R3/R5/R6/R7/R8/R9): edge time = per-CU
// lane-transaction processing: TA ~1.5cy/cache-line (stream + divergent
// gather lines) + LDS-atomic ~2cy/matched-lane. Structural floor ~50us.
// Refuted alternatives: global-atomic scatter (R4: fabric RMW, 200MB
// WRITE, 314us), branchless (R6: 3x lane-work, +49us), nontemporal (R7:
// killed L2 retention, +30us), cooperative fusion (R10: grid.sync across
// 8 XCDs ~150us; residue proved to be fixed harness overhead, not
// inter-dispatch gap).
__device__ __forceinline__ void proc4(const float* __restrict__ rates,
                                      float* __restrict__ bin, int base_node,
                                      int4 dd, int4 ss, float4 ww) {
    unsigned ex = (unsigned)(dd.x - base_node);
    unsigned ey = (unsigned)(dd.y - base_node);
    unsigned ez = (unsigned)(dd.z - base_node);
    unsigned ew = (unsigned)(dd.w - base_node);
    if (ex < BIN_SZ) atomicAdd(&bin[ex], rates[ss.x] * ww.x);
    if (ey < BIN_SZ) atomicAdd(&bin[ey], rates[ss.y] * ww.y);
    if (ez < BIN_SZ) atomicAdd(&bin[ez], rates[ss.z] * ww.z);
    if (ew < BIN_SZ) atomicAdd(&bin[ew], rates[ss.w] * ww.w);
}

__global__ __launch_bounds__(BLOCK) void edge_bin_kernel(
        const float* __restrict__ rates,
        const float* __restrict__ weights,
        const int* __restrict__ src,
        const int* __restrict__ dst,
        float* __restrict__ part,      // [n_chunks][N_NODES]
        int n_chunks, int edges_per_chunk) {
    __shared__ float bin[BIN_SZ];

    // Bijective XCD swizzle (m204): contiguous vbids per XCD => the 4 sibling
    // bin-blocks of a chunk share an XCD's L2 (R3-verified: FETCH 189->43 MB).
    // grid=256: 32 blocks = 8 whole chunks per XCD.
    const int nb  = gridDim.x;
    const int hb  = blockIdx.x;
    const int q   = nb / NXCD, r = nb % NXCD;
    const int xcd = hb % NXCD, pos = hb / NXCD;
    const int vbid = (xcd < r ? xcd * (q + 1) : r * (q + 1) + (xcd - r) * q) + pos;

    const int b = vbid % K_BINS;
    const int c = vbid / K_BINS;
    const int base_node = b * BIN_SZ;

    // Vectorized zero-init: 6250 float4 stores.
    {
        float4* bz = (float4*)bin;
        const float4 z = make_float4(0.f, 0.f, 0.f, 0.f);
        for (int i = threadIdx.x; i < (BIN_SZ >> 2); i += BLOCK) bz[i] = z;
    }
    __syncthreads();

    const long e0 = (long)c * edges_per_chunk;
    const int nq = edges_per_chunk >> 4;              // groups of 16 edges
    const int4*   s4 = (const int4*)(src + e0);
    const int4*   d4 = (const int4*)(dst + e0);
    const float4* w4 = (const float4*)(weights + e0);

    for (int i = threadIdx.x; i < nq; i += BLOCK) {
        const int4*   dp = d4 + 4 * i;
        const int4*   sp = s4 + 4 * i;
        const float4* wp = w4 + 4 * i;
        int4   d0 = dp[0], d1 = dp[1], d2 = dp[2], d3 = dp[3];
        int4   sA = sp[0], sB = sp[1], sC = sp[2], sD = sp[3];
        float4 wA = wp[0], wB = wp[1], wC = wp[2], wD = wp[3];
        proc4(rates, bin, base_node, d0, sA, wA);
        proc4(rates, bin, base_node, d1, sB, wB);
        proc4(rates, bin, base_node, d2, sC, wC);
        proc4(rates, bin, base_node, d3, sD, wD);
    }
    __syncthreads();

    // Vectorized flush (K=4: 4*25000 == N_NODES, clamp kept for safety
    // against future K changes).
    const int flush_n = min(BIN_SZ, N_NODES - base_node);
    float4* outp = (float4*)(part + (size_t)c * N_NODES + base_node);
    const float4* binv = (const float4*)bin;
    for (int i = threadIdx.x; i < (flush_n >> 2); i += BLOCK) {
        outp[i] = binv[i];
    }
}

// Node epilogue, float4-vectorized (N_NODES % 4 == 0): sum the n_chunks
// copies, then out[v] = (-r + 10^gain * tanh((is_input?ext:syn)+baseline))/tau
__global__ void node_kernel(const float* __restrict__ rates,
                            const float* __restrict__ gain,
                            const float* __restrict__ time_constant,
                            const float* __restrict__ baseline,
                            const float* __restrict__ ext_input,
                            const int*   __restrict__ is_input,
                            const float* __restrict__ part,
                            float* __restrict__ out,
                            int n_chunks) {
    const int t = blockIdx.x * blockDim.x + threadIdx.x;  // group of 4 nodes
    if (t >= (N_NODES >> 2)) return;

    float4 a0 = make_float4(0.f, 0.f, 0.f, 0.f);
    float4 a1 = make_float4(0.f, 0.f, 0.f, 0.f);
    float4 a2 = make_float4(0.f, 0.f, 0.f, 0.f);
    float4 a3 = make_float4(0.f, 0.f, 0.f, 0.f);
    int k = 0;
    for (; k + 3 < n_chunks; k += 4) {
        float4 p0 = ((const float4*)(part + (size_t)(k + 0) * N_NODES))[t];
        float4 p1 = ((const float4*)(part + (size_t)(k + 1) * N_NODES))[t];
        float4 p2 = ((const float4*)(part + (size_t)(k + 2) * N_NODES))[t];
        float4 p3 = ((const float4*)(part + (size_t)(k + 3) * N_NODES))[t];
        a0.x += p0.x; a0.y += p0.y; a0.z += p0.z; a0.w += p0.w;
        a1.x += p1.x; a1.y += p1.y; a1.z += p1.z; a1.w += p1.w;
        a2.x += p2.x; a2.y += p2.y; a2.z += p2.z; a2.w += p2.w;
        a3.x += p3.x; a3.y += p3.y; a3.z += p3.z; a3.w += p3.w;
    }
    for (; k < n_chunks; ++k) {
        float4 p = ((const float4*)(part + (size_t)k * N_NODES))[t];
        a0.x += p.x; a0.y += p.y; a0.z += p.z; a0.w += p.w;
    }
    float sx = (a0.x + a1.x) + (a2.x + a3.x);
    float sy = (a0.y + a1.y) + (a2.y + a3.y);
    float sz = (a0.z + a1.z) + (a2.z + a3.z);
    float sw = (a0.w + a1.w) + (a2.w + a3.w);

    float4 r   = ((const float4*)rates)[t];
    float4 g   = ((const float4*)gain)[t];
    float4 tc  = ((const float4*)time_constant)[t];
    float4 bl  = ((const float4*)baseline)[t];
    float4 ext = ((const float4*)ext_input)[t];
    int4   ii  = ((const int4*)is_input)[t];

    float4 o;
    o.x = (-r.x + exp2f(g.x * LOG2_10) * tanhf((ii.x ? ext.x : sx) + bl.x)) / tc.x;
    o.y = (-r.y + exp2f(g.y * LOG2_10) * tanhf((ii.y ? ext.y : sy) + bl.y)) / tc.y;
    o.z = (-r.z + exp2f(g.z * LOG2_10) * tanhf((ii.z ? ext.z : sz) + bl.z)) / tc.z;
    o.w = (-r.w + exp2f(g.w * LOG2_10) * tanhf((ii.w ? ext.w : sw) + bl.w)) / tc.w;
    ((float4*)out)[t] = o;
}

extern "C" void kernel_launch(void* const* d_in, const int* in_sizes, int n_in,
                              void* d_out, int out_size, void* d_ws, size_t ws_size,
                              hipStream_t stream) {
    const float* rates         = (const float*)d_in[0];
    const float* weights       = (const float*)d_in[1];
    const float* gain          = (const float*)d_in[2];
    const float* time_constant = (const float*)d_in[3];
    const float* baseline      = (const float*)d_in[4];
    const float* ext_input     = (const float*)d_in[5];
    const int*   src           = (const int*)d_in[6];
    const int*   dst           = (const int*)d_in[7];
    const int*   is_input      = (const int*)d_in[8];
    float* out  = (float*)d_out;
    float* part = (float*)d_ws;

    // 64 chunks -> grid 4*64 = 256 blocks = exactly 1/CU at 100 KB LDS.
    // 256 % 8 == 0 keeps the XCD swizzle bijective and chunk-aligned
    // (32 blocks = 8 whole chunks per XCD). All candidates give
    // edges_per_chunk % 16 == 0. part needs 64*400KB = 25.6 MB of ws.
    static const int cand[] = {64, 32, 16, 8, 4, 2, 1};
    int n_chunks = 1;
    for (int i = 0; i < (int)(sizeof(cand)/sizeof(cand[0])); ++i) {
        if ((size_t)cand[i] * N_NODES * sizeof(float) <= ws_size) { n_chunks = cand[i]; break; }
    }
    int edges_per_chunk = N_EDGES / n_chunks;

    int grid_e = K_BINS * n_chunks;
    edge_bin_kernel<<<grid_e, BLOCK, 0, stream>>>(rates, weights, src, dst,
                                                  part, n_chunks, edges_per_chunk);

    int block = 256;
    int grid_n = ((N_NODES >> 2) + block - 1) / block;   // 25,000 float4 groups
    node_kernel<<<grid_n, block, 0, stream>>>(rates, gain, time_constant, baseline,
                                              ext_input, is_input, part, out, n_chunks);
}